// Round 5
// baseline (6727.534 us; speedup 1.0000x reference)
//
#include <hip/hip_runtime.h>
#include <hip/hip_bf16.h>

using bf16 = __hip_bfloat16;
typedef __bf16 bfv8 __attribute__((ext_vector_type(8)));
typedef float f32x4 __attribute__((ext_vector_type(4)));

#define DEVI __device__ __forceinline__

constexpr int L_ = 12, C_ = 768, H_ = 12, FF_ = 3072, DH_ = 64;
constexpr int B_ = 64, P_ = 196, T_ = 40;
constexpr int N_ = T_ + 1 + P_;       // 237
constexpr int M_ = B_ * N_;           // 15168
constexpr int MPAD = 15360;           // 60*256
constexpr int NKV = 256;
constexpr int BP_ = B_ * P_;          // 12544 = 49*256

// ---------------- workspace layout ----------------
constexpr size_t OFF_X   = 0;
constexpr size_t SZ_X    = (size_t)MPAD * C_ * 4;
constexpr size_t OFF_H   = OFF_X + SZ_X;
constexpr size_t SZ_H    = (size_t)MPAD * C_ * 2;
constexpr size_t OFF_Q   = OFF_H + SZ_H;
constexpr size_t SZ_QKV1 = (size_t)B_ * H_ * NKV * DH_ * 2;
constexpr size_t OFF_K   = OFF_Q + SZ_QKV1;
constexpr size_t OFF_V   = OFF_K + SZ_QKV1;
constexpr size_t OFF_O   = OFF_V + SZ_QKV1;
constexpr size_t SZ_O    = SZ_H;
constexpr size_t OFF_FFH = OFF_O + SZ_O;
constexpr size_t SZ_FFH  = (size_t)MPAD * FF_ * 2;
constexpr size_t OFF_WB  = OFF_FFH + SZ_FFH;
constexpr size_t SZ_WB   = (size_t)(2304 + 768 + 3072 + 3072) * 768 * 2;
constexpr size_t WS_NEED = OFF_WB + SZ_WB;
// aliases (used only before the layer loop; FFH region is free then)
constexpr size_t OFF_PTMP = OFF_FFH;                             // f32 [12544,768]
constexpr size_t OFF_VISB = OFF_FFH + (size_t)40 * 1024 * 1024;  // bf16 [12544,768]
constexpr size_t OFF_PWB  = OFF_WB;                              // bf16 [768,768]

DEVI void gld_lds16(const bf16* g, bf16* l) {
  __builtin_amdgcn_global_load_lds((__attribute__((address_space(1))) void*)(g),
                                   (__attribute__((address_space(3))) void*)(l), 16, 0, 0);
}

// bijective XCD-aware swizzle (m204), col-tile fastest within each XCD chunk
DEVI void swz_tiles(int bid, int G, int NTC, int& bm, int& bn) {
  const int qq = G >> 3, rr = G & 7;
  const int xcd = bid & 7, base = bid >> 3;
  const int lin = (xcd < rr ? xcd * (qq + 1) : rr * (qq + 1) + (xcd - rr) * qq) + base;
  bm = lin / NTC;
  bn = lin - bm * NTC;
}

DEVI uint packbf(float lo, float hi) {
  union { struct { bf16 x, y; } h; uint u; } r;
  r.h.x = __float2bfloat16(lo); r.h.y = __float2bfloat16(hi);
  return r.u;
}

DEVI float gelu_f(float v) {
  const float p = v * (1.5957691f + 0.07135481f * v * v) * 1.442695041f;
  const float d = exp2f(-p);
  return v / (1.f + d);
}

// ------- triple-buffered depth-2 GEMM: C = A[M,K] * W[N,K]^T + bias -------
// BM=256, BN=128, 512 threads (8 waves as 4M x 2N), BK=64, LDS 3x48KB.
// EPI: 0 f32 store, 1 qkv scatter, 2 x += , 3 gelu->bf16, 4 outf2 = outf + v
template <int EPI>
__global__ __launch_bounds__(512, 2) void gemm3s(
    const bf16* __restrict__ A, const bf16* __restrict__ W,
    const float* __restrict__ bias, float* __restrict__ outf,
    float* __restrict__ outf2, bf16* __restrict__ outb,
    bf16* __restrict__ qb, bf16* __restrict__ kb, bf16* __restrict__ vb,
    int Nout, int K, int Mvalid, int NTC) {
  extern __shared__ __align__(16) char lds[];
  constexpr int SLOT = 49152;           // (256+128)*64*2 bytes
  constexpr int BOFF = 32768;           // B region inside a slot

  const int tid = threadIdx.x, wid = tid >> 6, lane = tid & 63;
  const int wm = wid >> 1, wn = wid & 1;
  int bm, bn;
  swz_tiles(blockIdx.x, gridDim.x, NTC, bm, bn);
  const size_t arow0 = (size_t)bm * 256;
  const size_t brow0 = (size_t)bn * 128;

  // pre-swizzled global source (rule #21); LDS dest stays linear for gload_lds
  const int xr = ((lane & 7) ^ (lane >> 3)) * 8;
  const size_t aoff0 = (arow0 + (size_t)wid * 32 + (lane >> 3)) * K + xr;
  const size_t boff0 = (brow0 + (size_t)wid * 16 + (lane >> 3)) * K + xr;

  f32x4 acc[4][4];
#pragma unroll
  for (int m = 0; m < 4; m++)
#pragma unroll
    for (int n = 0; n < 4; n++) acc[m][n] = (f32x4){0.f, 0.f, 0.f, 0.f};

  auto STAGE = [&](int t, int so) {
    char* slot = lds + so;
    const bf16* Ag = A + aoff0 + (size_t)t * 64;
#pragma unroll
    for (int i = 0; i < 4; i++)
      gld_lds16(Ag + (size_t)i * 8 * K, (bf16*)(slot + (wid * 32 + i * 8) * 128));
    const bf16* Wg = W + boff0 + (size_t)t * 64;
#pragma unroll
    for (int i = 0; i < 2; i++)
      gld_lds16(Wg + (size_t)i * 8 * K, (bf16*)(slot + BOFF + (wid * 16 + i * 8) * 128));
  };

  const int la = lane & 15, g = lane >> 4;
  auto COMPUTE = [&](int so) {
    const char* slot = lds + so;
#pragma unroll
    for (int ks = 0; ks < 2; ks++) {
      bfv8 bfr[4];
#pragma unroll
      for (int n = 0; n < 4; n++) {
        const int r = wn * 64 + n * 16 + la;
        bfr[n] = *(const bfv8*)(slot + BOFF + r * 128 + (((ks * 4 + g) ^ (r & 7)) * 16));
      }
#pragma unroll
      for (int m = 0; m < 4; m++) {
        const int r = wm * 64 + m * 16 + la;
        bfv8 af = *(const bfv8*)(slot + r * 128 + (((ks * 4 + g) ^ (r & 7)) * 16));
#pragma unroll
        for (int n = 0; n < 4; n++)
          acc[m][n] = __builtin_amdgcn_mfma_f32_16x16x32_bf16(af, bfr[n], acc[m][n], 0, 0, 0);
      }
    }
  };

  const int NT = K >> 6;
  STAGE(0, 0);
  STAGE(1, SLOT);
  int cs = 0, sp = 2 * SLOT;
  for (int t = 0; t < NT; ++t) {
    if (t + 2 < NT) {
      STAGE(t + 2, sp);
      sp = (sp == 2 * SLOT) ? 0 : sp + SLOT;
      asm volatile("s_waitcnt vmcnt(12)" ::: "memory");
    } else if (t + 1 < NT) {
      asm volatile("s_waitcnt vmcnt(6)" ::: "memory");
    } else {
      asm volatile("s_waitcnt vmcnt(0)" ::: "memory");
    }
    asm volatile("s_barrier" ::: "memory");
    COMPUTE(cs);
    cs = (cs == 2 * SLOT) ? 0 : cs + SLOT;
    asm volatile("s_barrier" ::: "memory");
  }

  // ---------------- epilogue ----------------
  const int row0 = (int)arow0 + wm * 64;
  const int col0 = (int)brow0 + wn * 64;
  float bv[4];
#pragma unroll
  for (int n = 0; n < 4; n++) bv[n] = bias[col0 + n * 16 + la];

  if constexpr (EPI == 0 || EPI == 2 || EPI == 4) {
#pragma unroll
    for (int n = 0; n < 4; n++) {
      const int colb = col0 + n * 16 + la;
#pragma unroll
      for (int m = 0; m < 4; m++)
#pragma unroll
        for (int j = 0; j < 4; j++) {
          const int row = row0 + m * 16 + g * 4 + j;
          const float v = acc[m][n][j] + bv[n];
          if constexpr (EPI == 0) outf[(size_t)row * Nout + colb] = v;
          else if constexpr (EPI == 2) outf[(size_t)row * Nout + colb] += v;
          else { if (row < Mvalid) outf2[(size_t)row * Nout + colb] = outf[(size_t)row * Nout + colb] + v; }
        }
    }
  } else if constexpr (EPI == 3) {
#pragma unroll
    for (int m = 0; m < 4; m++)
#pragma unroll
      for (int j = 0; j < 4; j++) {
        const int row = row0 + m * 16 + g * 4 + j;
#pragma unroll
        for (int n = 0; n < 4; n++) {
          const float v = gelu_f(acc[m][n][j] + bv[n]);
          const float p = __shfl_xor(v, 1);
          if (!(lane & 1))
            *(uint*)(outb + (size_t)row * Nout + col0 + n * 16 + la) = packbf(v, p);
        }
      }
  } else {  // EPI == 1: qkv scatter, packed pairs
#pragma unroll
    for (int m = 0; m < 4; m++)
#pragma unroll
      for (int j = 0; j < 4; j++) {
        const int row = row0 + m * 16 + g * 4 + j;
        const bool ok = row < Mvalid;
        const int bI = row / N_;
        const int nI = row - bI * N_;
#pragma unroll
        for (int n = 0; n < 4; n++) {
          const int colb = col0 + n * 16 + la;
          const float v = acc[m][n][j] + bv[n];
          const float p = __shfl_xor(v, 1);
          if (ok && !(lane & 1)) {
            const int s = colb / C_;
            const int rem = colb - s * C_;
            const int hh = rem >> 6, dd = rem & 63;
            bf16* dst = (s == 0) ? qb : (s == 1) ? kb : vb;
            *(uint*)(dst + (((size_t)bI * H_ + hh) * NKV + nI) * DH_ + dd) = packbf(v, p);
          }
        }
      }
  }
}

// ---------------- per-layer weight conversion ----------------
__global__ __launch_bounds__(256) void conv_weights_k(
    const float* __restrict__ wq, const float* __restrict__ wp,
    const float* __restrict__ wf1, const float* __restrict__ wf2,
    bf16* __restrict__ dst) {
  const long n0 = 2304L * 768 / 4, n1 = 768L * 768 / 4;
  const long n2 = 3072L * 768 / 4;
  const long tot = n0 + n1 + 2 * n2;
  for (long i = (long)blockIdx.x * 256 + threadIdx.x; i < tot; i += (long)gridDim.x * 256) {
    const float* s; long off;
    if (i < n0) { s = wq; off = i; }
    else if (i < n0 + n1) { s = wp; off = i - n0; }
    else if (i < n0 + n1 + n2) { s = wf1; off = i - n0 - n1; }
    else { s = wf2; off = i - n0 - n1 - n2; }
    float4 v = ((const float4*)s)[off];
    union { short4 q; bf16 h[4]; } u;
    u.h[0] = __float2bfloat16(v.x); u.h[1] = __float2bfloat16(v.y);
    u.h[2] = __float2bfloat16(v.z); u.h[3] = __float2bfloat16(v.w);
    ((short4*)dst)[i] = u.q;
  }
}

__global__ __launch_bounds__(256) void f32_to_bf16_k(const float* __restrict__ s,
                                                     bf16* __restrict__ d, long n4) {
  long i = (long)blockIdx.x * 256 + threadIdx.x;
  long stride = (long)gridDim.x * 256;
  for (; i < n4; i += stride) {
    float4 v = ((const float4*)s)[i];
    union { short4 q; bf16 h[4]; } u;
    u.h[0] = __float2bfloat16(v.x); u.h[1] = __float2bfloat16(v.y);
    u.h[2] = __float2bfloat16(v.z); u.h[3] = __float2bfloat16(v.w);
    ((short4*)d)[i] = u.q;
  }
}

// ---------------- embedding + LN (eps 1e-5) ----------------
__global__ __launch_bounds__(256) void embed_kernel(
    const float* __restrict__ ptmp, const int* __restrict__ txt_in,
    const float* __restrict__ wemb, const float* __restrict__ tpos,
    const float* __restrict__ vpos, const float* __restrict__ vcls,
    const float* __restrict__ vmod, const float* __restrict__ tmod,
    const float* __restrict__ vnw, const float* __restrict__ vnb,
    const float* __restrict__ tnw, const float* __restrict__ tnb,
    float* __restrict__ x) {
  const int row = blockIdx.x;
  const int tid = threadIdx.x;
  if (row >= M_) {
    for (int i = tid; i < C_; i += 256) x[(size_t)row * C_ + i] = 0.f;
    return;
  }
  const int b = row / N_, n = row - (row / N_) * N_;
  const bool istxt = n < T_;
  float e[3];
#pragma unroll
  for (int i = 0; i < 3; i++) {
    const int c = tid + i * 256;
    float v;
    if (istxt) {
      v = wemb[(size_t)txt_in[b * T_ + n] * C_ + c] + tpos[n * C_ + c] + tmod[c];
    } else {
      const int vi = n - T_;
      const float base = (vi == 0) ? vcls[c] : ptmp[((size_t)b * P_ + (vi - 1)) * C_ + c];
      v = base + vpos[vi * C_ + c] + vmod[c];
    }
    e[i] = v;
  }
  float s = e[0] + e[1] + e[2];
  float s2 = e[0] * e[0] + e[1] * e[1] + e[2] * e[2];
#pragma unroll
  for (int d = 1; d < 64; d <<= 1) { s += __shfl_xor(s, d); s2 += __shfl_xor(s2, d); }
  __shared__ float rs[4], rs2[4];
  const int wid = tid >> 6, lane = tid & 63;
  if (lane == 0) { rs[wid] = s; rs2[wid] = s2; }
  __syncthreads();
  s = rs[0] + rs[1] + rs[2] + rs[3];
  s2 = rs2[0] + rs2[1] + rs2[2] + rs2[3];
  const float mean = s * (1.f / C_);
  const float var = s2 * (1.f / C_) - mean * mean;
  const float rr = rsqrtf(var + 1e-5f);
  const float* w = istxt ? tnw : vnw;
  const float* bb = istxt ? tnb : vnb;
#pragma unroll
  for (int i = 0; i < 3; i++) {
    const int c = tid + i * 256;
    x[(size_t)row * C_ + c] = (e[i] - mean) * rr * w[c] + bb[c];
  }
}

// ---------------- layer LN: f32 x -> bf16 out ----------------
__global__ __launch_bounds__(256) void ln_rows(const float* __restrict__ x,
                                               const float* __restrict__ w,
                                               const float* __restrict__ b,
                                               bf16* __restrict__ out, float eps) {
  const int row = blockIdx.x * 4 + (threadIdx.x >> 6);
  const int lane = threadIdx.x & 63;
  if (row >= MPAD) return;
  bf16* op = out + (size_t)row * C_;
  if (row >= M_) {
#pragma unroll
    for (int i = 0; i < 3; i++)
      *(short4*)(op + (lane + 64 * i) * 4) = make_short4(0, 0, 0, 0);
    return;
  }
  const float4* xp = (const float4*)(x + (size_t)row * C_);
  float4 v[3];
  float s = 0.f, s2 = 0.f;
#pragma unroll
  for (int i = 0; i < 3; i++) {
    v[i] = xp[lane + 64 * i];
    s += v[i].x + v[i].y + v[i].z + v[i].w;
    s2 += v[i].x * v[i].x + v[i].y * v[i].y + v[i].z * v[i].z + v[i].w * v[i].w;
  }
#pragma unroll
  for (int d = 1; d < 64; d <<= 1) { s += __shfl_xor(s, d); s2 += __shfl_xor(s2, d); }
  const float mean = s * (1.f / C_);
  const float rr = rsqrtf(s2 * (1.f / C_) - mean * mean + eps);
#pragma unroll
  for (int i = 0; i < 3; i++) {
    const int c0 = (lane + 64 * i) * 4;
    const float4 w4 = *(const float4*)(w + c0);
    const float4 b4 = *(const float4*)(b + c0);
    union { short4 s4; bf16 h[4]; } u;
    u.h[0] = __float2bfloat16((v[i].x - mean) * rr * w4.x + b4.x);
    u.h[1] = __float2bfloat16((v[i].y - mean) * rr * w4.y + b4.y);
    u.h[2] = __float2bfloat16((v[i].z - mean) * rr * w4.z + b4.z);
    u.h[3] = __float2bfloat16((v[i].w - mean) * rr * w4.w + b4.w);
    *(short4*)(op + c0) = u.s4;
  }
}

// ---------------- fused attention ----------------
DEVI float maskval(const int* __restrict__ tm, const int* __restrict__ vm, int b, int j) {
  if (j < T_) return tm[b * T_ + j] ? 1.f : 0.f;
  if (j == T_) return 1.f;
  if (j < N_) return vm[b * P_ + (j - T_ - 1)] ? 1.f : 0.f;
  return 0.f;
}

__global__ __launch_bounds__(256) void attn_fused(
    const bf16* __restrict__ qb, const bf16* __restrict__ kb,
    const bf16* __restrict__ vb, const int* __restrict__ txt_mask,
    const int* __restrict__ vis_mask, bf16* __restrict__ ob) {
  __shared__ alignas(16) __bf16 Vt[64 * 264];
  __shared__ alignas(16) __bf16 Ps[64 * 264];
  const int qblk = blockIdx.x;
  const int bh = blockIdx.y;
  const int b = bh / H_, hh = bh - b * H_;
  const int tid = threadIdx.x, wid = tid >> 6, lane = tid & 63;

  const __bf16* Vg = (const __bf16*)(vb + (size_t)bh * NKV * DH_);
#pragma unroll
  for (int it = 0; it < 8; it++) {
    const int r = lane + 64 * (it & 3);
    const int c8 = (wid + 4 * (it >> 2)) * 8;
    bfv8 v;
    if (r < N_) v = *(const bfv8*)(Vg + (size_t)r * DH_ + c8);
    else { union { int4 i; bfv8 x; } z; z.i = make_int4(0,0,0,0); v = z.x; }
#pragma unroll
    for (int d = 0; d < 8; d++) Vt[(c8 + d) * 264 + r] = v[d];
  }

  const int qbase = qblk * 64 + wid * 16;
  const __bf16* Qg = (const __bf16*)(qb + (size_t)bh * NKV * DH_);
  const __bf16* Kg = (const __bf16*)(kb + (size_t)bh * NKV * DH_);
  bfv8 aq[2];
#pragma unroll
  for (int kk = 0; kk < 2; kk++)
    aq[kk] = *(const bfv8*)(Qg + (size_t)(qbase + (lane & 15)) * DH_ + kk * 32 + (lane >> 4) * 8);

  f32x4 acc[16];
#pragma unroll
  for (int f = 0; f < 16; f++) acc[f] = (f32x4){0.f, 0.f, 0.f, 0.f};
#pragma unroll
  for (int f = 0; f < 16; f++) {
#pragma unroll
    for (int kk = 0; kk < 2; kk++) {
      bfv8 bk = *(const bfv8*)(Kg + (size_t)(f * 16 + (lane & 15)) * DH_ + kk * 32 + (lane >> 4) * 8);
      acc[f] = __builtin_amdgcn_mfma_f32_16x16x32_bf16(aq[kk], bk, acc[f], 0, 0, 0);
    }
  }

  float cm[16];
#pragma unroll
  for (int f = 0; f < 16; f++)
    cm[f] = maskval(txt_mask, vis_mask, b, f * 16 + (lane & 15));

  const float scale = 0.125f;
#pragma unroll
  for (int j = 0; j < 4; j++) {
    const int qr = qbase + (lane >> 4) * 4 + j;
    const float qm = (qr < N_) ? maskval(txt_mask, vis_mask, b, qr) : 1.f;
    float sv[16];
    float mx = -3.0e38f;
#pragma unroll
    for (int f = 0; f < 16; f++) {
      const int col = f * 16 + (lane & 15);
      float sc;
      if (col >= N_) sc = -INFINITY;
      else if (qm * cm[f] == 0.f) sc = -1e30f;
      else sc = acc[f][j] * scale;
      sv[f] = sc;
      mx = fmaxf(mx, sc);
    }
#pragma unroll
    for (int d = 1; d < 16; d <<= 1) mx = fmaxf(mx, __shfl_xor(mx, d));
    float sum = 0.f;
#pragma unroll
    for (int f = 0; f < 16; f++) { const float p = expf(sv[f] - mx); sv[f] = p; sum += p; }
#pragma unroll
    for (int d = 1; d < 16; d <<= 1) sum += __shfl_xor(sum, d);
    const float inv = 1.f / sum;
    const int ql = wid * 16 + (lane >> 4) * 4 + j;
#pragma unroll
    for (int f = 0; f < 16; f++)
      Ps[ql * 264 + f * 16 + (lane & 15)] = (__bf16)(sv[f] * inv);
  }

  __syncthreads();

  f32x4 oacc[4];
#pragma unroll
  for (int n = 0; n < 4; n++) oacc[n] = (f32x4){0.f, 0.f, 0.f, 0.f};
#pragma unroll
  for (int kk = 0; kk < 8; kk++) {
    bfv8 ap = *(const bfv8*)&Ps[(wid * 16 + (lane & 15)) * 264 + kk * 32 + (lane >> 4) * 8];
#pragma unroll
    for (int n = 0; n < 4; n++) {
      bfv8 bv = *(const bfv8*)&Vt[(n * 16 + (lane & 15)) * 264 + kk * 32 + (lane >> 4) * 8];
      oacc[n] = __builtin_amdgcn_mfma_f32_16x16x32_bf16(ap, bv, oacc[n], 0, 0, 0);
    }
  }
#pragma unroll
  for (int n = 0; n < 4; n++)
#pragma unroll
    for (int j = 0; j < 4; j++) {
      const int q = qbase + (lane >> 4) * 4 + j;
      if (q < N_)
        ob[((size_t)b * N_ + q) * C_ + hh * 64 + n * 16 + (lane & 15)] =
            __float2bfloat16(oacc[n][j]);
    }
}

// ---------------- host ----------------
extern "C" void kernel_launch(void* const* d_in, const int* in_sizes, int n_in,
                              void* d_out, int out_size, void* d_ws, size_t ws_size,
                              hipStream_t stream) {
  const float* vis_in  = (const float*)d_in[0];
  const int*   txt_in  = (const int*)d_in[1];
  const int*   vis_mask = (const int*)d_in[2];
  const int*   txt_mask = (const int*)d_in[3];
  const float* patch_w = (const float*)d_in[4];
  const float* patch_b = (const float*)d_in[5];
  const float* w_embed = (const float*)d_in[6];
  const float* t_pos   = (const float*)d_in[7];
  const float* v_pos   = (const float*)d_in[8];
  const float* v_cls   = (const float*)d_in[9];
  const float* v_mod   = (const float*)d_in[10];
  const float* t_mod   = (const float*)d_in[11];
  const float* vn_w = (const float*)d_in[12];
  const float* vn_b = (const float*)d_in[13];
  const float* tn_w = (const float*)d_in[14];
  const float* tn_b = (const float*)d_in[15];
  const float* qkv_w = (const float*)d_in[16];
  const float* qkv_b = (const float*)d_in[17];
  const float* proj_w = (const float*)d_in[18];
  const float* proj_b = (const float*)d_in[19];
  const float* n1_w = (const float*)d_in[20];
  const float* n1_b = (const float*)d_in[21];
  const float* n2_w = (const float*)d_in[22];
  const float* n2_b = (const float*)d_in[23];
  const float* fc1_w = (const float*)d_in[24];
  const float* fc1_b = (const float*)d_in[25];
  const float* fc2_w = (const float*)d_in[26];
  const float* fc2_b = (const float*)d_in[27];

  char* ws = (char*)d_ws;
  if (ws_size < WS_NEED) {
    hipMemsetAsync(d_out, 0, (size_t)out_size * 4, stream);
    return;
  }
  float* x    = (float*)(ws + OFF_X);
  bf16* h     = (bf16*)(ws + OFF_H);
  bf16* qbuf  = (bf16*)(ws + OFF_Q);
  bf16* kbuf  = (bf16*)(ws + OFF_K);
  bf16* vbuf  = (bf16*)(ws + OFF_V);
  bf16* obuf  = (bf16*)(ws + OFF_O);
  bf16* ffh   = (bf16*)(ws + OFF_FFH);
  bf16* wq    = (bf16*)(ws + OFF_WB);
  bf16* wp    = wq + (size_t)2304 * 768;
  bf16* wf1   = wp + (size_t)768 * 768;
  bf16* wf2   = wf1 + (size_t)3072 * 768;
  float* ptmp = (float*)(ws + OFF_PTMP);
  bf16* visb  = (bf16*)(ws + OFF_VISB);
  bf16* pwb   = (bf16*)(ws + OFF_PWB);

  constexpr int LDS3 = 3 * 49152;  // 147456
  (void)hipFuncSetAttribute((const void*)gemm3s<0>, hipFuncAttributeMaxDynamicSharedMemorySize, LDS3);
  (void)hipFuncSetAttribute((const void*)gemm3s<1>, hipFuncAttributeMaxDynamicSharedMemorySize, LDS3);
  (void)hipFuncSetAttribute((const void*)gemm3s<2>, hipFuncAttributeMaxDynamicSharedMemorySize, LDS3);
  (void)hipFuncSetAttribute((const void*)gemm3s<3>, hipFuncAttributeMaxDynamicSharedMemorySize, LDS3);
  (void)hipFuncSetAttribute((const void*)gemm3s<4>, hipFuncAttributeMaxDynamicSharedMemorySize, LDS3);

  // patch projection
  f32_to_bf16_k<<<1024, 256, 0, stream>>>(vis_in, visb, (long)BP_ * C_ / 4);
  f32_to_bf16_k<<<256, 256, 0, stream>>>(patch_w, pwb, (long)C_ * C_ / 4);
  gemm3s<0><<<(BP_ / 256) * (C_ / 128), 512, LDS3, stream>>>(
      visb, pwb, patch_b, ptmp, nullptr, nullptr, nullptr, nullptr, nullptr,
      C_, C_, BP_, C_ / 128);
  embed_kernel<<<MPAD, 256, 0, stream>>>(ptmp, txt_in, w_embed, t_pos, v_pos, v_cls,
                                         v_mod, t_mod, vn_w, vn_b, tn_w, tn_b, x);

  for (int l = 0; l < L_; l++) {
    conv_weights_k<<<2048, 256, 0, stream>>>(
        qkv_w + (size_t)l * 2304 * 768, proj_w + (size_t)l * 768 * 768,
        fc1_w + (size_t)l * 3072 * 768, fc2_w + (size_t)l * 768 * 3072, wq);

    ln_rows<<<MPAD / 4, 256, 0, stream>>>(x, n1_w + l * C_, n1_b + l * C_, h, 1e-6f);
    gemm3s<1><<<(MPAD / 256) * (2304 / 128), 512, LDS3, stream>>>(
        h, wq, qkv_b + (size_t)l * 2304, nullptr, nullptr, nullptr, qbuf, kbuf, vbuf,
        2304, C_, M_, 2304 / 128);
    attn_fused<<<dim3(4, B_ * H_), 256, 0, stream>>>(qbuf, kbuf, vbuf, txt_mask,
                                                     vis_mask, obuf);
    gemm3s<2><<<(MPAD / 256) * (C_ / 128), 512, LDS3, stream>>>(
        obuf, wp, proj_b + (size_t)l * C_, x, nullptr, nullptr, nullptr, nullptr,
        nullptr, C_, C_, M_, C_ / 128);
    ln_rows<<<MPAD / 4, 256, 0, stream>>>(x, n2_w + l * C_, n2_b + l * C_, h, 1e-6f);
    gemm3s<3><<<(MPAD / 256) * (FF_ / 128), 512, LDS3, stream>>>(
        h, wf1, fc1_b + (size_t)l * FF_, nullptr, nullptr, ffh, nullptr, nullptr,
        nullptr, FF_, C_, M_, FF_ / 128);
    if (l < L_ - 1) {
      gemm3s<2><<<(MPAD / 256) * (C_ / 128), 512, LDS3, stream>>>(
          ffh, wf2, fc2_b + (size_t)l * C_, x, nullptr, nullptr, nullptr, nullptr,
          nullptr, C_, FF_, M_, C_ / 128);
    } else {
      gemm3s<4><<<(MPAD / 256) * (C_ / 128), 512, LDS3, stream>>>(
          ffh, wf2, fc2_b + (size_t)l * C_, x, (float*)d_out, nullptr, nullptr,
          nullptr, nullptr, C_, FF_, M_, C_ / 128);
    }
  }
}

// Round 6
// 6693.853 us; speedup vs baseline: 1.0050x; 1.0050x over previous
//
#include <hip/hip_runtime.h>
#include <hip/hip_bf16.h>

using bf16 = __hip_bfloat16;
typedef __bf16 bfv8 __attribute__((ext_vector_type(8)));
typedef float f32x4 __attribute__((ext_vector_type(4)));

#define DEVI __device__ __forceinline__

constexpr int L_ = 12, C_ = 768, H_ = 12, FF_ = 3072, DH_ = 64;
constexpr int B_ = 64, P_ = 196, T_ = 40;
constexpr int N_ = T_ + 1 + P_;       // 237
constexpr int M_ = B_ * N_;           // 15168
constexpr int MPAD = 15360;           // 60*256
constexpr int NKV = 256;
constexpr int BP_ = B_ * P_;          // 12544 = 49*256

// ---------------- workspace layout ----------------
constexpr size_t OFF_X   = 0;
constexpr size_t SZ_X    = (size_t)MPAD * C_ * 4;
constexpr size_t OFF_H   = OFF_X + SZ_X;
constexpr size_t SZ_H    = (size_t)MPAD * C_ * 2;
constexpr size_t OFF_Q   = OFF_H + SZ_H;
constexpr size_t SZ_QKV1 = (size_t)B_ * H_ * NKV * DH_ * 2;
constexpr size_t OFF_K   = OFF_Q + SZ_QKV1;
constexpr size_t OFF_V   = OFF_K + SZ_QKV1;
constexpr size_t OFF_O   = OFF_V + SZ_QKV1;
constexpr size_t SZ_O    = SZ_H;
constexpr size_t OFF_FFH = OFF_O + SZ_O;
constexpr size_t SZ_FFH  = (size_t)MPAD * FF_ * 2;
constexpr size_t OFF_WB  = OFF_FFH + SZ_FFH;
constexpr size_t SZ_WB   = (size_t)(2304 + 768 + 3072 + 3072) * 768 * 2;
constexpr size_t WS_NEED = OFF_WB + SZ_WB;
// aliases (used only before the layer loop; FFH region is free then)
constexpr size_t OFF_PTMP = OFF_FFH;                             // f32 [12544,768]
constexpr size_t OFF_VISB = OFF_FFH + (size_t)40 * 1024 * 1024;  // bf16 [12544,768]
constexpr size_t OFF_PWB  = OFF_WB;                              // bf16 [768,768]

DEVI void gld_lds16(const bf16* g, bf16* l) {
  __builtin_amdgcn_global_load_lds((__attribute__((address_space(1))) void*)(g),
                                   (__attribute__((address_space(3))) void*)(l), 16, 0, 0);
}

// bijective XCD-aware swizzle (m204), col-tile fastest within each XCD chunk
DEVI void swz_tiles(int bid, int G, int NTC, int& bm, int& bn) {
  const int qq = G >> 3, rr = G & 7;
  const int xcd = bid & 7, base = bid >> 3;
  const int lin = (xcd < rr ? xcd * (qq + 1) : rr * (qq + 1) + (xcd - rr) * qq) + base;
  bm = lin / NTC;
  bn = lin - bm * NTC;
}

DEVI uint packbf(float lo, float hi) {
  union { struct { bf16 x, y; } h; uint u; } r;
  r.h.x = __float2bfloat16(lo); r.h.y = __float2bfloat16(hi);
  return r.u;
}

DEVI float gelu_f(float v) {
  const float p = v * (1.5957691f + 0.07135481f * v * v) * 1.442695041f;
  const float d = exp2f(-p);
  return v / (1.f + d);
}

// ------- 8-phase-style pipelined GEMM: C = A[M,K] * W[N,K]^T + bias -------
// BM=256, BN=128, 512 threads (8 waves as 4M x 2N, per-wave 64x64), BK=64.
// 3 LDS slots; compute slot t%3, stage slot (t+2)%3; vmcnt(6) per K-tile.
// Per K-tile: 2 phases, each {ds_read frags | stage 3 loads | s_barrier |
// setprio(1) 16xMFMA setprio(0)}.
// EPI: 0 f32 store, 1 qkv scatter, 2 x += , 3 gelu->bf16, 4 outf2 = outf + v
template <int EPI>
__global__ __launch_bounds__(512, 1) void gemm8p(
    const bf16* __restrict__ A, const bf16* __restrict__ W,
    const float* __restrict__ bias, float* __restrict__ outf,
    float* __restrict__ outf2, bf16* __restrict__ outb,
    bf16* __restrict__ qb, bf16* __restrict__ kb, bf16* __restrict__ vb,
    int Nout, int K, int Mvalid, int NTC) {
  extern __shared__ __align__(16) char lds[];
  constexpr int SLOT = 49152;           // A 32KB + B 16KB
  constexpr int BOFF = 32768;

  const int tid = threadIdx.x, wid = tid >> 6, lane = tid & 63;
  const int wm = wid >> 1, wn = wid & 1;
  int bm, bn;
  swz_tiles(blockIdx.x, gridDim.x, NTC, bm, bn);
  const size_t arow0 = (size_t)bm * 256;
  const size_t brow0 = (size_t)bn * 128;

  // pre-swizzled global source (rule #21); LDS dest stays linear for gload_lds
  const int xr = ((lane & 7) ^ (lane >> 3)) * 8;
  const size_t aoff0 = (arow0 + (size_t)wid * 32 + (lane >> 3)) * K + xr;
  const size_t boff0 = (brow0 + (size_t)wid * 16 + (lane >> 3)) * K + xr;

  f32x4 acc[4][4];
#pragma unroll
  for (int m = 0; m < 4; m++)
#pragma unroll
    for (int n = 0; n < 4; n++) acc[m][n] = (f32x4){0.f, 0.f, 0.f, 0.f};

  // stage halves: a = A chunks 0..2, b = A chunk 3 + B chunks 0..1 (6 loads total)
  auto STGa = [&](int t, int so) {
    const bf16* Ag = A + aoff0 + (size_t)t * 64;
    char* s = lds + so;
#pragma unroll
    for (int i = 0; i < 3; i++)
      gld_lds16(Ag + (size_t)i * 8 * K, (bf16*)(s + (wid * 32 + i * 8) * 128));
  };
  auto STGb = [&](int t, int so) {
    const bf16* Ag = A + aoff0 + (size_t)t * 64;
    const bf16* Wg = W + boff0 + (size_t)t * 64;
    char* s = lds + so;
    gld_lds16(Ag + (size_t)24 * K, (bf16*)(s + (wid * 32 + 24) * 128));
#pragma unroll
    for (int i = 0; i < 2; i++)
      gld_lds16(Wg + (size_t)i * 8 * K, (bf16*)(s + BOFF + (wid * 16 + i * 8) * 128));
  };

  const int la = lane & 15, g = lane >> 4;

  const int NT = K >> 6;
  STGa(0, 0); STGb(0, 0);
  STGa(1, SLOT); STGb(1, SLOT);
  asm volatile("s_waitcnt vmcnt(6)" ::: "memory");
  __builtin_amdgcn_s_barrier();

  int cs = 0;
  for (int t = 0; t < NT; ++t) {
    const int so = cs;
    int sn = cs + 2 * SLOT; if (sn >= 3 * SLOT) sn -= 3 * SLOT;
    const char* sa = lds + so;
    const bool pf = (t + 2 < NT);

    // ---- phase A: A-frags + B-frags n0/n1, stage 3, MFMA n in {0,1}
    bfv8 af[8], bf0[4];
#pragma unroll
    for (int m = 0; m < 4; m++)
#pragma unroll
      for (int ks = 0; ks < 2; ks++) {
        const int r = wm * 64 + m * 16 + la;
        af[m * 2 + ks] = *(const bfv8*)(sa + r * 128 + (((ks * 4 + g) ^ (r & 7)) * 16));
      }
#pragma unroll
    for (int n = 0; n < 2; n++)
#pragma unroll
      for (int ks = 0; ks < 2; ks++) {
        const int r = wn * 64 + n * 16 + la;
        bf0[n * 2 + ks] = *(const bfv8*)(sa + BOFF + r * 128 + (((ks * 4 + g) ^ (r & 7)) * 16));
      }
    if (pf) STGa(t + 2, sn);
    __builtin_amdgcn_s_barrier();
    __builtin_amdgcn_s_setprio(1);
#pragma unroll
    for (int ks = 0; ks < 2; ks++)
#pragma unroll
      for (int m = 0; m < 4; m++)
#pragma unroll
        for (int n = 0; n < 2; n++)
          acc[m][n] = __builtin_amdgcn_mfma_f32_16x16x32_bf16(af[m * 2 + ks], bf0[n * 2 + ks],
                                                              acc[m][n], 0, 0, 0);
    __builtin_amdgcn_s_setprio(0);

    // ---- phase B: B-frags n2/n3, stage 3, MFMA n in {2,3}
    bfv8 bf1[4];
#pragma unroll
    for (int n = 0; n < 2; n++)
#pragma unroll
      for (int ks = 0; ks < 2; ks++) {
        const int r = wn * 64 + (n + 2) * 16 + la;
        bf1[n * 2 + ks] = *(const bfv8*)(sa + BOFF + r * 128 + (((ks * 4 + g) ^ (r & 7)) * 16));
      }
    if (pf) STGb(t + 2, sn);
    __builtin_amdgcn_s_barrier();
    __builtin_amdgcn_s_setprio(1);
#pragma unroll
    for (int ks = 0; ks < 2; ks++)
#pragma unroll
      for (int m = 0; m < 4; m++)
#pragma unroll
        for (int n = 0; n < 2; n++)
          acc[m][n + 2] = __builtin_amdgcn_mfma_f32_16x16x32_bf16(af[m * 2 + ks], bf1[n * 2 + ks],
                                                                  acc[m][n + 2], 0, 0, 0);
    __builtin_amdgcn_s_setprio(0);

    // ---- K-tile end: counted drain (t+1's 6 loads are the oldest in flight)
    if (pf) asm volatile("s_waitcnt vmcnt(6)" ::: "memory");
    else    asm volatile("s_waitcnt vmcnt(0)" ::: "memory");
    __builtin_amdgcn_s_barrier();
    cs = (cs == 2 * SLOT) ? 0 : cs + SLOT;
  }

  // ---------------- epilogue ----------------
  const int row0 = (int)arow0 + wm * 64;
  const int col0 = (int)brow0 + wn * 64;
  float bv[4];
#pragma unroll
  for (int n = 0; n < 4; n++) bv[n] = bias[col0 + n * 16 + la];

  if constexpr (EPI == 0 || EPI == 2 || EPI == 4) {
#pragma unroll
    for (int n = 0; n < 4; n++) {
      const int colb = col0 + n * 16 + la;
#pragma unroll
      for (int m = 0; m < 4; m++)
#pragma unroll
        for (int j = 0; j < 4; j++) {
          const int row = row0 + m * 16 + g * 4 + j;
          const float v = acc[m][n][j] + bv[n];
          if constexpr (EPI == 0) outf[(size_t)row * Nout + colb] = v;
          else if constexpr (EPI == 2) outf[(size_t)row * Nout + colb] += v;
          else { if (row < Mvalid) outf2[(size_t)row * Nout + colb] = outf[(size_t)row * Nout + colb] + v; }
        }
    }
  } else if constexpr (EPI == 3) {
#pragma unroll
    for (int m = 0; m < 4; m++)
#pragma unroll
      for (int j = 0; j < 4; j++) {
        const int row = row0 + m * 16 + g * 4 + j;
#pragma unroll
        for (int n = 0; n < 4; n++) {
          const float v = gelu_f(acc[m][n][j] + bv[n]);
          const float p = __shfl_xor(v, 1);
          if (!(lane & 1))
            *(uint*)(outb + (size_t)row * Nout + col0 + n * 16 + la) = packbf(v, p);
        }
      }
  } else {  // EPI == 1: qkv scatter, packed pairs
#pragma unroll
    for (int m = 0; m < 4; m++)
#pragma unroll
      for (int j = 0; j < 4; j++) {
        const int row = row0 + m * 16 + g * 4 + j;
        const bool ok = row < Mvalid;
        const int bI = row / N_;
        const int nI = row - bI * N_;
#pragma unroll
        for (int n = 0; n < 4; n++) {
          const int colb = col0 + n * 16 + la;
          const float v = acc[m][n][j] + bv[n];
          const float p = __shfl_xor(v, 1);
          if (ok && !(lane & 1)) {
            const int s = colb / C_;
            const int rem = colb - s * C_;
            const int hh = rem >> 6, dd = rem & 63;
            bf16* dst = (s == 0) ? qb : (s == 1) ? kb : vb;
            *(uint*)(dst + (((size_t)bI * H_ + hh) * NKV + nI) * DH_ + dd) = packbf(v, p);
          }
        }
      }
  }
}

// ---------------- per-layer weight conversion ----------------
__global__ __launch_bounds__(256) void conv_weights_k(
    const float* __restrict__ wq, const float* __restrict__ wp,
    const float* __restrict__ wf1, const float* __restrict__ wf2,
    bf16* __restrict__ dst) {
  const long n0 = 2304L * 768 / 4, n1 = 768L * 768 / 4;
  const long n2 = 3072L * 768 / 4;
  const long tot = n0 + n1 + 2 * n2;
  for (long i = (long)blockIdx.x * 256 + threadIdx.x; i < tot; i += (long)gridDim.x * 256) {
    const float* s; long off;
    if (i < n0) { s = wq; off = i; }
    else if (i < n0 + n1) { s = wp; off = i - n0; }
    else if (i < n0 + n1 + n2) { s = wf1; off = i - n0 - n1; }
    else { s = wf2; off = i - n0 - n1 - n2; }
    float4 v = ((const float4*)s)[off];
    union { short4 q; bf16 h[4]; } u;
    u.h[0] = __float2bfloat16(v.x); u.h[1] = __float2bfloat16(v.y);
    u.h[2] = __float2bfloat16(v.z); u.h[3] = __float2bfloat16(v.w);
    ((short4*)dst)[i] = u.q;
  }
}

__global__ __launch_bounds__(256) void f32_to_bf16_k(const float* __restrict__ s,
                                                     bf16* __restrict__ d, long n4) {
  long i = (long)blockIdx.x * 256 + threadIdx.x;
  long stride = (long)gridDim.x * 256;
  for (; i < n4; i += stride) {
    float4 v = ((const float4*)s)[i];
    union { short4 q; bf16 h[4]; } u;
    u.h[0] = __float2bfloat16(v.x); u.h[1] = __float2bfloat16(v.y);
    u.h[2] = __float2bfloat16(v.z); u.h[3] = __float2bfloat16(v.w);
    ((short4*)d)[i] = u.q;
  }
}

// ---------------- embedding + LN (eps 1e-5) ----------------
__global__ __launch_bounds__(256) void embed_kernel(
    const float* __restrict__ ptmp, const int* __restrict__ txt_in,
    const float* __restrict__ wemb, const float* __restrict__ tpos,
    const float* __restrict__ vpos, const float* __restrict__ vcls,
    const float* __restrict__ vmod, const float* __restrict__ tmod,
    const float* __restrict__ vnw, const float* __restrict__ vnb,
    const float* __restrict__ tnw, const float* __restrict__ tnb,
    float* __restrict__ x) {
  const int row = blockIdx.x;
  const int tid = threadIdx.x;
  if (row >= M_) {
    for (int i = tid; i < C_; i += 256) x[(size_t)row * C_ + i] = 0.f;
    return;
  }
  const int b = row / N_, n = row - (row / N_) * N_;
  const bool istxt = n < T_;
  float e[3];
#pragma unroll
  for (int i = 0; i < 3; i++) {
    const int c = tid + i * 256;
    float v;
    if (istxt) {
      v = wemb[(size_t)txt_in[b * T_ + n] * C_ + c] + tpos[n * C_ + c] + tmod[c];
    } else {
      const int vi = n - T_;
      const float base = (vi == 0) ? vcls[c] : ptmp[((size_t)b * P_ + (vi - 1)) * C_ + c];
      v = base + vpos[vi * C_ + c] + vmod[c];
    }
    e[i] = v;
  }
  float s = e[0] + e[1] + e[2];
  float s2 = e[0] * e[0] + e[1] * e[1] + e[2] * e[2];
#pragma unroll
  for (int d = 1; d < 64; d <<= 1) { s += __shfl_xor(s, d); s2 += __shfl_xor(s2, d); }
  __shared__ float rs[4], rs2[4];
  const int wid = tid >> 6, lane = tid & 63;
  if (lane == 0) { rs[wid] = s; rs2[wid] = s2; }
  __syncthreads();
  s = rs[0] + rs[1] + rs[2] + rs[3];
  s2 = rs2[0] + rs2[1] + rs2[2] + rs2[3];
  const float mean = s * (1.f / C_);
  const float var = s2 * (1.f / C_) - mean * mean;
  const float rr = rsqrtf(var + 1e-5f);
  const float* w = istxt ? tnw : vnw;
  const float* bb = istxt ? tnb : vnb;
#pragma unroll
  for (int i = 0; i < 3; i++) {
    const int c = tid + i * 256;
    x[(size_t)row * C_ + c] = (e[i] - mean) * rr * w[c] + bb[c];
  }
}

// ---------------- layer LN: f32 x -> bf16 out ----------------
__global__ __launch_bounds__(256) void ln_rows(const float* __restrict__ x,
                                               const float* __restrict__ w,
                                               const float* __restrict__ b,
                                               bf16* __restrict__ out, float eps) {
  const int row = blockIdx.x * 4 + (threadIdx.x >> 6);
  const int lane = threadIdx.x & 63;
  if (row >= MPAD) return;
  bf16* op = out + (size_t)row * C_;
  if (row >= M_) {
#pragma unroll
    for (int i = 0; i < 3; i++)
      *(short4*)(op + (lane + 64 * i) * 4) = make_short4(0, 0, 0, 0);
    return;
  }
  const float4* xp = (const float4*)(x + (size_t)row * C_);
  float4 v[3];
  float s = 0.f, s2 = 0.f;
#pragma unroll
  for (int i = 0; i < 3; i++) {
    v[i] = xp[lane + 64 * i];
    s += v[i].x + v[i].y + v[i].z + v[i].w;
    s2 += v[i].x * v[i].x + v[i].y * v[i].y + v[i].z * v[i].z + v[i].w * v[i].w;
  }
#pragma unroll
  for (int d = 1; d < 64; d <<= 1) { s += __shfl_xor(s, d); s2 += __shfl_xor(s2, d); }
  const float mean = s * (1.f / C_);
  const float rr = rsqrtf(s2 * (1.f / C_) - mean * mean + eps);
#pragma unroll
  for (int i = 0; i < 3; i++) {
    const int c0 = (lane + 64 * i) * 4;
    const float4 w4 = *(const float4*)(w + c0);
    const float4 b4 = *(const float4*)(b + c0);
    union { short4 s4; bf16 h[4]; } u;
    u.h[0] = __float2bfloat16((v[i].x - mean) * rr * w4.x + b4.x);
    u.h[1] = __float2bfloat16((v[i].y - mean) * rr * w4.y + b4.y);
    u.h[2] = __float2bfloat16((v[i].z - mean) * rr * w4.z + b4.z);
    u.h[3] = __float2bfloat16((v[i].w - mean) * rr * w4.w + b4.w);
    *(short4*)(op + c0) = u.s4;
  }
}

// ---------------- fused attention ----------------
DEVI float maskval(const int* __restrict__ tm, const int* __restrict__ vm, int b, int j) {
  if (j < T_) return tm[b * T_ + j] ? 1.f : 0.f;
  if (j == T_) return 1.f;
  if (j < N_) return vm[b * P_ + (j - T_ - 1)] ? 1.f : 0.f;
  return 0.f;
}

__global__ __launch_bounds__(256) void attn_fused(
    const bf16* __restrict__ qb, const bf16* __restrict__ kb,
    const bf16* __restrict__ vb, const int* __restrict__ txt_mask,
    const int* __restrict__ vis_mask, bf16* __restrict__ ob) {
  __shared__ alignas(16) __bf16 Vt[64 * 264];
  __shared__ alignas(16) __bf16 Ps[64 * 264];
  const int qblk = blockIdx.x;
  const int bh = blockIdx.y;
  const int b = bh / H_, hh = bh - b * H_;
  const int tid = threadIdx.x, wid = tid >> 6, lane = tid & 63;

  const __bf16* Vg = (const __bf16*)(vb + (size_t)bh * NKV * DH_);
#pragma unroll
  for (int it = 0; it < 8; it++) {
    const int r = lane + 64 * (it & 3);
    const int c8 = (wid + 4 * (it >> 2)) * 8;
    bfv8 v;
    if (r < N_) v = *(const bfv8*)(Vg + (size_t)r * DH_ + c8);
    else { union { int4 i; bfv8 x; } z; z.i = make_int4(0,0,0,0); v = z.x; }
#pragma unroll
    for (int d = 0; d < 8; d++) Vt[(c8 + d) * 264 + r] = v[d];
  }

  const int qbase = qblk * 64 + wid * 16;
  const __bf16* Qg = (const __bf16*)(qb + (size_t)bh * NKV * DH_);
  const __bf16* Kg = (const __bf16*)(kb + (size_t)bh * NKV * DH_);
  bfv8 aq[2];
#pragma unroll
  for (int kk = 0; kk < 2; kk++)
    aq[kk] = *(const bfv8*)(Qg + (size_t)(qbase + (lane & 15)) * DH_ + kk * 32 + (lane >> 4) * 8);

  f32x4 acc[16];
#pragma unroll
  for (int f = 0; f < 16; f++) acc[f] = (f32x4){0.f, 0.f, 0.f, 0.f};
#pragma unroll
  for (int f = 0; f < 16; f++) {
#pragma unroll
    for (int kk = 0; kk < 2; kk++) {
      bfv8 bk = *(const bfv8*)(Kg + (size_t)(f * 16 + (lane & 15)) * DH_ + kk * 32 + (lane >> 4) * 8);
      acc[f] = __builtin_amdgcn_mfma_f32_16x16x32_bf16(aq[kk], bk, acc[f], 0, 0, 0);
    }
  }

  float cm[16];
#pragma unroll
  for (int f = 0; f < 16; f++)
    cm[f] = maskval(txt_mask, vis_mask, b, f * 16 + (lane & 15));

  const float scale = 0.125f;
#pragma unroll
  for (int j = 0; j < 4; j++) {
    const int qr = qbase + (lane >> 4) * 4 + j;
    const float qm = (qr < N_) ? maskval(txt_mask, vis_mask, b, qr) : 1.f;
    float sv[16];
    float mx = -3.0e38f;
#pragma unroll
    for (int f = 0; f < 16; f++) {
      const int col = f * 16 + (lane & 15);
      float sc;
      if (col >= N_) sc = -INFINITY;
      else if (qm * cm[f] == 0.f) sc = -1e30f;
      else sc = acc[f][j] * scale;
      sv[f] = sc;
      mx = fmaxf(mx, sc);
    }
#pragma unroll
    for (int d = 1; d < 16; d <<= 1) mx = fmaxf(mx, __shfl_xor(mx, d));
    float sum = 0.f;
#pragma unroll
    for (int f = 0; f < 16; f++) { const float p = expf(sv[f] - mx); sv[f] = p; sum += p; }
#pragma unroll
    for (int d = 1; d < 16; d <<= 1) sum += __shfl_xor(sum, d);
    const float inv = 1.f / sum;
    const int ql = wid * 16 + (lane >> 4) * 4 + j;
#pragma unroll
    for (int f = 0; f < 16; f++)
      Ps[ql * 264 + f * 16 + (lane & 15)] = (__bf16)(sv[f] * inv);
  }

  __syncthreads();

  f32x4 oacc[4];
#pragma unroll
  for (int n = 0; n < 4; n++) oacc[n] = (f32x4){0.f, 0.f, 0.f, 0.f};
#pragma unroll
  for (int kk = 0; kk < 8; kk++) {
    bfv8 ap = *(const bfv8*)&Ps[(wid * 16 + (lane & 15)) * 264 + kk * 32 + (lane >> 4) * 8];
#pragma unroll
    for (int n = 0; n < 4; n++) {
      bfv8 bv = *(const bfv8*)&Vt[(n * 16 + (lane & 15)) * 264 + kk * 32 + (lane >> 4) * 8];
      oacc[n] = __builtin_amdgcn_mfma_f32_16x16x32_bf16(ap, bv, oacc[n], 0, 0, 0);
    }
  }
#pragma unroll
  for (int n = 0; n < 4; n++)
#pragma unroll
    for (int j = 0; j < 4; j++) {
      const int q = qbase + (lane >> 4) * 4 + j;
      if (q < N_)
        ob[((size_t)b * N_ + q) * C_ + hh * 64 + n * 16 + (lane & 15)] =
            __float2bfloat16(oacc[n][j]);
    }
}

// ---------------- host ----------------
extern "C" void kernel_launch(void* const* d_in, const int* in_sizes, int n_in,
                              void* d_out, int out_size, void* d_ws, size_t ws_size,
                              hipStream_t stream) {
  const float* vis_in  = (const float*)d_in[0];
  const int*   txt_in  = (const int*)d_in[1];
  const int*   vis_mask = (const int*)d_in[2];
  const int*   txt_mask = (const int*)d_in[3];
  const float* patch_w = (const float*)d_in[4];
  const float* patch_b = (const float*)d_in[5];
  const float* w_embed = (const float*)d_in[6];
  const float* t_pos   = (const float*)d_in[7];
  const float* v_pos   = (const float*)d_in[8];
  const float* v_cls   = (const float*)d_in[9];
  const float* v_mod   = (const float*)d_in[10];
  const float* t_mod   = (const float*)d_in[11];
  const float* vn_w = (const float*)d_in[12];
  const float* vn_b = (const float*)d_in[13];
  const float* tn_w = (const float*)d_in[14];
  const float* tn_b = (const float*)d_in[15];
  const float* qkv_w = (const float*)d_in[16];
  const float* qkv_b = (const float*)d_in[17];
  const float* proj_w = (const float*)d_in[18];
  const float* proj_b = (const float*)d_in[19];
  const float* n1_w = (const float*)d_in[20];
  const float* n1_b = (const float*)d_in[21];
  const float* n2_w = (const float*)d_in[22];
  const float* n2_b = (const float*)d_in[23];
  const float* fc1_w = (const float*)d_in[24];
  const float* fc1_b = (const float*)d_in[25];
  const float* fc2_w = (const float*)d_in[26];
  const float* fc2_b = (const float*)d_in[27];

  char* ws = (char*)d_ws;
  if (ws_size < WS_NEED) {
    hipMemsetAsync(d_out, 0, (size_t)out_size * 4, stream);
    return;
  }
  float* x    = (float*)(ws + OFF_X);
  bf16* h     = (bf16*)(ws + OFF_H);
  bf16* qbuf  = (bf16*)(ws + OFF_Q);
  bf16* kbuf  = (bf16*)(ws + OFF_K);
  bf16* vbuf  = (bf16*)(ws + OFF_V);
  bf16* obuf  = (bf16*)(ws + OFF_O);
  bf16* ffh   = (bf16*)(ws + OFF_FFH);
  bf16* wq    = (bf16*)(ws + OFF_WB);
  bf16* wp    = wq + (size_t)2304 * 768;
  bf16* wf1   = wp + (size_t)768 * 768;
  bf16* wf2   = wf1 + (size_t)3072 * 768;
  float* ptmp = (float*)(ws + OFF_PTMP);
  bf16* visb  = (bf16*)(ws + OFF_VISB);
  bf16* pwb   = (bf16*)(ws + OFF_PWB);

  constexpr int LDS3 = 3 * 49152;  // 147456
  (void)hipFuncSetAttribute((const void*)gemm8p<0>, hipFuncAttributeMaxDynamicSharedMemorySize, LDS3);
  (void)hipFuncSetAttribute((const void*)gemm8p<1>, hipFuncAttributeMaxDynamicSharedMemorySize, LDS3);
  (void)hipFuncSetAttribute((const void*)gemm8p<2>, hipFuncAttributeMaxDynamicSharedMemorySize, LDS3);
  (void)hipFuncSetAttribute((const void*)gemm8p<3>, hipFuncAttributeMaxDynamicSharedMemorySize, LDS3);
  (void)hipFuncSetAttribute((const void*)gemm8p<4>, hipFuncAttributeMaxDynamicSharedMemorySize, LDS3);

  // patch projection
  f32_to_bf16_k<<<1024, 256, 0, stream>>>(vis_in, visb, (long)BP_ * C_ / 4);
  f32_to_bf16_k<<<256, 256, 0, stream>>>(patch_w, pwb, (long)C_ * C_ / 4);
  gemm8p<0><<<(BP_ / 256) * (C_ / 128), 512, LDS3, stream>>>(
      visb, pwb, patch_b, ptmp, nullptr, nullptr, nullptr, nullptr, nullptr,
      C_, C_, BP_, C_ / 128);
  embed_kernel<<<MPAD, 256, 0, stream>>>(ptmp, txt_in, w_embed, t_pos, v_pos, v_cls,
                                         v_mod, t_mod, vn_w, vn_b, tn_w, tn_b, x);

  for (int l = 0; l < L_; l++) {
    conv_weights_k<<<2048, 256, 0, stream>>>(
        qkv_w + (size_t)l * 2304 * 768, proj_w + (size_t)l * 768 * 768,
        fc1_w + (size_t)l * 3072 * 768, fc2_w + (size_t)l * 768 * 3072, wq);

    ln_rows<<<MPAD / 4, 256, 0, stream>>>(x, n1_w + l * C_, n1_b + l * C_, h, 1e-6f);
    gemm8p<1><<<(MPAD / 256) * (2304 / 128), 512, LDS3, stream>>>(
        h, wq, qkv_b + (size_t)l * 2304, nullptr, nullptr, nullptr, qbuf, kbuf, vbuf,
        2304, C_, M_, 2304 / 128);
    attn_fused<<<dim3(4, B_ * H_), 256, 0, stream>>>(qbuf, kbuf, vbuf, txt_mask,
                                                     vis_mask, obuf);
    gemm8p<2><<<(MPAD / 256) * (C_ / 128), 512, LDS3, stream>>>(
        obuf, wp, proj_b + (size_t)l * C_, x, nullptr, nullptr, nullptr, nullptr,
        nullptr, C_, C_, M_, C_ / 128);
    ln_rows<<<MPAD / 4, 256, 0, stream>>>(x, n2_w + l * C_, n2_b + l * C_, h, 1e-6f);
    gemm8p<3><<<(MPAD / 256) * (FF_ / 128), 512, LDS3, stream>>>(
        h, wf1, fc1_b + (size_t)l * FF_, nullptr, nullptr, ffh, nullptr, nullptr,
        nullptr, FF_, C_, M_, FF_ / 128);
    if (l < L_ - 1) {
      gemm8p<2><<<(MPAD / 256) * (C_ / 128), 512, LDS3, stream>>>(
          ffh, wf2, fc2_b + (size_t)l * C_, x, nullptr, nullptr, nullptr, nullptr,
          nullptr, C_, FF_, M_, C_ / 128);
    } else {
      gemm8p<4><<<(MPAD / 256) * (C_ / 128), 512, LDS3, stream>>>(
          ffh, wf2, fc2_b + (size_t)l * C_, x, (float*)d_out, nullptr, nullptr,
          nullptr, nullptr, C_, FF_, M_, C_ / 128);
    }
  }
}

// Round 7
// 6018.629 us; speedup vs baseline: 1.1178x; 1.1122x over previous
//
#include <hip/hip_runtime.h>
#include <hip/hip_bf16.h>

using bf16 = __hip_bfloat16;
typedef __bf16 bfv8 __attribute__((ext_vector_type(8)));
typedef float f32x4 __attribute__((ext_vector_type(4)));

#define DEVI __device__ __forceinline__

constexpr int L_ = 12, C_ = 768, H_ = 12, FF_ = 3072, DH_ = 64;
constexpr int B_ = 64, P_ = 196, T_ = 40;
constexpr int N_ = T_ + 1 + P_;       // 237
constexpr int M_ = B_ * N_;           // 15168
constexpr int MPAD = 15360;           // 120*128
constexpr int NKV = 256;
constexpr int BP_ = B_ * P_;          // 12544 = 98*128

// ---------------- workspace layout ----------------
constexpr size_t OFF_X   = 0;
constexpr size_t SZ_X    = (size_t)MPAD * C_ * 4;
constexpr size_t OFF_H   = OFF_X + SZ_X;
constexpr size_t SZ_H    = (size_t)MPAD * C_ * 2;
constexpr size_t OFF_Q   = OFF_H + SZ_H;
constexpr size_t SZ_QKV1 = (size_t)B_ * H_ * NKV * DH_ * 2;
constexpr size_t OFF_K   = OFF_Q + SZ_QKV1;
constexpr size_t OFF_V   = OFF_K + SZ_QKV1;
constexpr size_t OFF_O   = OFF_V + SZ_QKV1;
constexpr size_t SZ_O    = SZ_H;
constexpr size_t OFF_FFH = OFF_O + SZ_O;
constexpr size_t SZ_FFH  = (size_t)MPAD * FF_ * 2;
constexpr size_t OFF_WB  = OFF_FFH + SZ_FFH;
constexpr size_t SZ_WB   = (size_t)(2304 + 768 + 3072 + 3072) * 768 * 2;
constexpr size_t WS_NEED = OFF_WB + SZ_WB;
// aliases (used only before the layer loop; FFH region is free then)
constexpr size_t OFF_PTMP = OFF_FFH;                             // f32 [12544,768]
constexpr size_t OFF_VISB = OFF_FFH + (size_t)40 * 1024 * 1024;  // bf16 [12544,768]
constexpr size_t OFF_PWB  = OFF_WB;                              // bf16 [768,768]

DEVI void gld_lds16(const bf16* g, bf16* l) {
  __builtin_amdgcn_global_load_lds((__attribute__((address_space(1))) void*)(g),
                                   (__attribute__((address_space(3))) void*)(l), 16, 0, 0);
}

// bijective XCD-aware swizzle (m204), col-tile fastest within each XCD chunk
DEVI void swz_tiles(int bid, int G, int NTC, int& bm, int& bn) {
  const int qq = G >> 3, rr = G & 7;
  const int xcd = bid & 7, base = bid >> 3;
  const int lin = (xcd < rr ? xcd * (qq + 1) : rr * (qq + 1) + (xcd - rr) * qq) + base;
  bm = lin / NTC;
  bn = lin - bm * NTC;
}

DEVI uint packbf(float lo, float hi) {
  union { struct { bf16 x, y; } h; uint u; } r;
  r.h.x = __float2bfloat16(lo); r.h.y = __float2bfloat16(hi);
  return r.u;
}

DEVI float gelu_f(float v) {
  const float p = v * (1.5957691f + 0.07135481f * v * v) * 1.442695041f;
  const float d = exp2f(-p);
  return v / (1.f + d);
}

// ---- multi-block GEMM: 128x128 tile, BK=32, 256 thr, static 32KB dbuf LDS ----
// Loop: STAGE(t+1,buf^1); vmcnt(4) [drains tile t's loads, keeps t+1 in flight];
// s_barrier; 8 ds_read + 16 MFMA; s_barrier.  3-5 blocks/CU hide the latency.
// LDS layout: row r (64B) holds logical 16B-chunk g at slot (g + (r>>1))&3 -> 2-way free.
// EPI: 0 f32 store, 1 qkv scatter, 2 x += , 3 gelu->bf16, 4 outf2 = outf + v
template <int EPI>
__global__ __launch_bounds__(256) void gemm_mb(
    const bf16* __restrict__ A, const bf16* __restrict__ W,
    const float* __restrict__ bias, float* __restrict__ outf,
    float* __restrict__ outf2, bf16* __restrict__ outb,
    bf16* __restrict__ qb, bf16* __restrict__ kb, bf16* __restrict__ vb,
    int Nout, int K, int Mvalid, int NTC) {
  __shared__ alignas(16) bf16 As[2][128 * 32];
  __shared__ alignas(16) bf16 Bs[2][128 * 32];

  const int tid = threadIdx.x, wid = tid >> 6, lane = tid & 63;
  const int wm = wid >> 1, wn = wid & 1;
  int bm, bn;
  swz_tiles(blockIdx.x, gridDim.x, NTC, bm, bn);
  const size_t arow0 = (size_t)bm * 128;
  const size_t brow0 = (size_t)bn * 128;

  // staging: issue i covers rows i*64 + (tid>>2), phys slot tid&3 holds
  // logical chunk ((tid&3) - ((tid>>3)&3)) & 3  (pre-swizzled source, rule #21)
  const int srow = tid >> 2;
  const int gch = ((tid & 3) - ((tid >> 3) & 3)) & 3;
  const bf16* pa0 = A + (arow0 + srow) * K + gch * 8;
  const bf16* pa1 = A + (arow0 + 64 + srow) * K + gch * 8;
  const bf16* pb0 = W + (brow0 + srow) * K + gch * 8;
  const bf16* pb1 = W + (brow0 + 64 + srow) * K + gch * 8;
  // uniform LDS dests (lane writes base + lane*16B)
  bf16* da0[2] = {&As[0][(wid * 16) * 32], &As[1][(wid * 16) * 32]};
  bf16* da1[2] = {&As[0][(64 + wid * 16) * 32], &As[1][(64 + wid * 16) * 32]};
  bf16* db0[2] = {&Bs[0][(wid * 16) * 32], &Bs[1][(wid * 16) * 32]};
  bf16* db1[2] = {&Bs[0][(64 + wid * 16) * 32], &Bs[1][(64 + wid * 16) * 32]};

  auto STAGE = [&](int t, int b) {
    const size_t k = (size_t)t * 32;
    gld_lds16(pa0 + k, da0[b]);
    gld_lds16(pa1 + k, da1[b]);
    gld_lds16(pb0 + k, db0[b]);
    gld_lds16(pb1 + k, db1[b]);
  };

  f32x4 acc[4][4];
#pragma unroll
  for (int m = 0; m < 4; m++)
#pragma unroll
    for (int n = 0; n < 4; n++) acc[m][n] = (f32x4){0.f, 0.f, 0.f, 0.f};

  const int la = lane & 15, g = lane >> 4;
  const int slot8 = ((g + (la >> 1)) & 3) * 8;   // same slot for every fragment row

  const int NT = K >> 5;
  STAGE(0, 0);
  for (int t = 0; t < NT; ++t) {
    const int b = t & 1;
    if (t + 1 < NT) {
      STAGE(t + 1, b ^ 1);
      asm volatile("s_waitcnt vmcnt(4)" ::: "memory");
    } else {
      asm volatile("s_waitcnt vmcnt(0)" ::: "memory");
    }
    asm volatile("s_barrier" ::: "memory");
    bfv8 af[4], bfr[4];
#pragma unroll
    for (int n = 0; n < 4; n++)
      bfr[n] = *(const bfv8*)&Bs[b][(wn * 64 + n * 16 + la) * 32 + slot8];
#pragma unroll
    for (int m = 0; m < 4; m++)
      af[m] = *(const bfv8*)&As[b][(wm * 64 + m * 16 + la) * 32 + slot8];
#pragma unroll
    for (int m = 0; m < 4; m++)
#pragma unroll
      for (int n = 0; n < 4; n++)
        acc[m][n] = __builtin_amdgcn_mfma_f32_16x16x32_bf16(af[m], bfr[n], acc[m][n], 0, 0, 0);
    asm volatile("s_barrier" ::: "memory");
  }

  // ---------------- epilogue ----------------
  const int row0 = (int)arow0 + wm * 64;
  const int col0 = (int)brow0 + wn * 64;
  float bv[4];
#pragma unroll
  for (int n = 0; n < 4; n++) bv[n] = bias[col0 + n * 16 + la];

  if constexpr (EPI == 0 || EPI == 2 || EPI == 4) {
#pragma unroll
    for (int n = 0; n < 4; n++) {
      const int colb = col0 + n * 16 + la;
#pragma unroll
      for (int m = 0; m < 4; m++)
#pragma unroll
        for (int j = 0; j < 4; j++) {
          const int row = row0 + m * 16 + g * 4 + j;
          const float v = acc[m][n][j] + bv[n];
          if constexpr (EPI == 0) outf[(size_t)row * Nout + colb] = v;
          else if constexpr (EPI == 2) outf[(size_t)row * Nout + colb] += v;
          else { if (row < Mvalid) outf2[(size_t)row * Nout + colb] = outf[(size_t)row * Nout + colb] + v; }
        }
    }
  } else if constexpr (EPI == 3) {
#pragma unroll
    for (int m = 0; m < 4; m++)
#pragma unroll
      for (int j = 0; j < 4; j++) {
        const int row = row0 + m * 16 + g * 4 + j;
#pragma unroll
        for (int n = 0; n < 4; n++) {
          const float v = gelu_f(acc[m][n][j] + bv[n]);
          const float p = __shfl_xor(v, 1);
          if (!(lane & 1))
            *(uint*)(outb + (size_t)row * Nout + col0 + n * 16 + la) = packbf(v, p);
        }
      }
  } else {  // EPI == 1: qkv scatter, packed pairs
#pragma unroll
    for (int m = 0; m < 4; m++)
#pragma unroll
      for (int j = 0; j < 4; j++) {
        const int row = row0 + m * 16 + g * 4 + j;
        const bool ok = row < Mvalid;
        const int bI = row / N_;
        const int nI = row - bI * N_;
#pragma unroll
        for (int n = 0; n < 4; n++) {
          const int colb = col0 + n * 16 + la;
          const float v = acc[m][n][j] + bv[n];
          const float p = __shfl_xor(v, 1);
          if (ok && !(lane & 1)) {
            const int s = colb / C_;
            const int rem = colb - s * C_;
            const int hh = rem >> 6, dd = rem & 63;
            bf16* dst = (s == 0) ? qb : (s == 1) ? kb : vb;
            *(uint*)(dst + (((size_t)bI * H_ + hh) * NKV + nI) * DH_ + dd) = packbf(v, p);
          }
        }
      }
  }
}

// ---------------- per-layer weight conversion ----------------
__global__ __launch_bounds__(256) void conv_weights_k(
    const float* __restrict__ wq, const float* __restrict__ wp,
    const float* __restrict__ wf1, const float* __restrict__ wf2,
    bf16* __restrict__ dst) {
  const long n0 = 2304L * 768 / 4, n1 = 768L * 768 / 4;
  const long n2 = 3072L * 768 / 4;
  const long tot = n0 + n1 + 2 * n2;
  for (long i = (long)blockIdx.x * 256 + threadIdx.x; i < tot; i += (long)gridDim.x * 256) {
    const float* s; long off;
    if (i < n0) { s = wq; off = i; }
    else if (i < n0 + n1) { s = wp; off = i - n0; }
    else if (i < n0 + n1 + n2) { s = wf1; off = i - n0 - n1; }
    else { s = wf2; off = i - n0 - n1 - n2; }
    float4 v = ((const float4*)s)[off];
    union { short4 q; bf16 h[4]; } u;
    u.h[0] = __float2bfloat16(v.x); u.h[1] = __float2bfloat16(v.y);
    u.h[2] = __float2bfloat16(v.z); u.h[3] = __float2bfloat16(v.w);
    ((short4*)dst)[i] = u.q;
  }
}

__global__ __launch_bounds__(256) void f32_to_bf16_k(const float* __restrict__ s,
                                                     bf16* __restrict__ d, long n4) {
  long i = (long)blockIdx.x * 256 + threadIdx.x;
  long stride = (long)gridDim.x * 256;
  for (; i < n4; i += stride) {
    float4 v = ((const float4*)s)[i];
    union { short4 q; bf16 h[4]; } u;
    u.h[0] = __float2bfloat16(v.x); u.h[1] = __float2bfloat16(v.y);
    u.h[2] = __float2bfloat16(v.z); u.h[3] = __float2bfloat16(v.w);
    ((short4*)d)[i] = u.q;
  }
}

// ---------------- embedding + LN (eps 1e-5) ----------------
__global__ __launch_bounds__(256) void embed_kernel(
    const float* __restrict__ ptmp, const int* __restrict__ txt_in,
    const float* __restrict__ wemb, const float* __restrict__ tpos,
    const float* __restrict__ vpos, const float* __restrict__ vcls,
    const float* __restrict__ vmod, const float* __restrict__ tmod,
    const float* __restrict__ vnw, const float* __restrict__ vnb,
    const float* __restrict__ tnw, const float* __restrict__ tnb,
    float* __restrict__ x) {
  const int row = blockIdx.x;
  const int tid = threadIdx.x;
  if (row >= M_) {
    for (int i = tid; i < C_; i += 256) x[(size_t)row * C_ + i] = 0.f;
    return;
  }
  const int b = row / N_, n = row - (row / N_) * N_;
  const bool istxt = n < T_;
  float e[3];
#pragma unroll
  for (int i = 0; i < 3; i++) {
    const int c = tid + i * 256;
    float v;
    if (istxt) {
      v = wemb[(size_t)txt_in[b * T_ + n] * C_ + c] + tpos[n * C_ + c] + tmod[c];
    } else {
      const int vi = n - T_;
      const float base = (vi == 0) ? vcls[c] : ptmp[((size_t)b * P_ + (vi - 1)) * C_ + c];
      v = base + vpos[vi * C_ + c] + vmod[c];
    }
    e[i] = v;
  }
  float s = e[0] + e[1] + e[2];
  float s2 = e[0] * e[0] + e[1] * e[1] + e[2] * e[2];
#pragma unroll
  for (int d = 1; d < 64; d <<= 1) { s += __shfl_xor(s, d); s2 += __shfl_xor(s2, d); }
  __shared__ float rs[4], rs2[4];
  const int wid = tid >> 6, lane = tid & 63;
  if (lane == 0) { rs[wid] = s; rs2[wid] = s2; }
  __syncthreads();
  s = rs[0] + rs[1] + rs[2] + rs[3];
  s2 = rs2[0] + rs2[1] + rs2[2] + rs2[3];
  const float mean = s * (1.f / C_);
  const float var = s2 * (1.f / C_) - mean * mean;
  const float rr = rsqrtf(var + 1e-5f);
  const float* w = istxt ? tnw : vnw;
  const float* bb = istxt ? tnb : vnb;
#pragma unroll
  for (int i = 0; i < 3; i++) {
    const int c = tid + i * 256;
    x[(size_t)row * C_ + c] = (e[i] - mean) * rr * w[c] + bb[c];
  }
}

// ---------------- layer LN: f32 x -> bf16 out ----------------
__global__ __launch_bounds__(256) void ln_rows(const float* __restrict__ x,
                                               const float* __restrict__ w,
                                               const float* __restrict__ b,
                                               bf16* __restrict__ out, float eps) {
  const int row = blockIdx.x * 4 + (threadIdx.x >> 6);
  const int lane = threadIdx.x & 63;
  if (row >= MPAD) return;
  bf16* op = out + (size_t)row * C_;
  if (row >= M_) {
#pragma unroll
    for (int i = 0; i < 3; i++)
      *(short4*)(op + (lane + 64 * i) * 4) = make_short4(0, 0, 0, 0);
    return;
  }
  const float4* xp = (const float4*)(x + (size_t)row * C_);
  float4 v[3];
  float s = 0.f, s2 = 0.f;
#pragma unroll
  for (int i = 0; i < 3; i++) {
    v[i] = xp[lane + 64 * i];
    s += v[i].x + v[i].y + v[i].z + v[i].w;
    s2 += v[i].x * v[i].x + v[i].y * v[i].y + v[i].z * v[i].z + v[i].w * v[i].w;
  }
#pragma unroll
  for (int d = 1; d < 64; d <<= 1) { s += __shfl_xor(s, d); s2 += __shfl_xor(s2, d); }
  const float mean = s * (1.f / C_);
  const float rr = rsqrtf(s2 * (1.f / C_) - mean * mean + eps);
#pragma unroll
  for (int i = 0; i < 3; i++) {
    const int c0 = (lane + 64 * i) * 4;
    const float4 w4 = *(const float4*)(w + c0);
    const float4 b4 = *(const float4*)(b + c0);
    union { short4 s4; bf16 h[4]; } u;
    u.h[0] = __float2bfloat16((v[i].x - mean) * rr * w4.x + b4.x);
    u.h[1] = __float2bfloat16((v[i].y - mean) * rr * w4.y + b4.y);
    u.h[2] = __float2bfloat16((v[i].z - mean) * rr * w4.z + b4.z);
    u.h[3] = __float2bfloat16((v[i].w - mean) * rr * w4.w + b4.w);
    *(short4*)(op + c0) = u.s4;
  }
}

// ---------------- fused attention ----------------
DEVI float maskval(const int* __restrict__ tm, const int* __restrict__ vm, int b, int j) {
  if (j < T_) return tm[b * T_ + j] ? 1.f : 0.f;
  if (j == T_) return 1.f;
  if (j < N_) return vm[b * P_ + (j - T_ - 1)] ? 1.f : 0.f;
  return 0.f;
}

__global__ __launch_bounds__(256) void attn_fused(
    const bf16* __restrict__ qb, const bf16* __restrict__ kb,
    const bf16* __restrict__ vb, const int* __restrict__ txt_mask,
    const int* __restrict__ vis_mask, bf16* __restrict__ ob) {
  __shared__ alignas(16) __bf16 Vt[64 * 264];
  __shared__ alignas(16) __bf16 Ps[64 * 264];
  const int qblk = blockIdx.x;
  const int bh = blockIdx.y;
  const int b = bh / H_, hh = bh - b * H_;
  const int tid = threadIdx.x, wid = tid >> 6, lane = tid & 63;

  const __bf16* Vg = (const __bf16*)(vb + (size_t)bh * NKV * DH_);
#pragma unroll
  for (int it = 0; it < 8; it++) {
    const int r = lane + 64 * (it & 3);
    const int c8 = (wid + 4 * (it >> 2)) * 8;
    bfv8 v;
    if (r < N_) v = *(const bfv8*)(Vg + (size_t)r * DH_ + c8);
    else { union { int4 i; bfv8 x; } z; z.i = make_int4(0,0,0,0); v = z.x; }
#pragma unroll
    for (int d = 0; d < 8; d++) Vt[(c8 + d) * 264 + r] = v[d];
  }

  const int qbase = qblk * 64 + wid * 16;
  const __bf16* Qg = (const __bf16*)(qb + (size_t)bh * NKV * DH_);
  const __bf16* Kg = (const __bf16*)(kb + (size_t)bh * NKV * DH_);
  bfv8 aq[2];
#pragma unroll
  for (int kk = 0; kk < 2; kk++)
    aq[kk] = *(const bfv8*)(Qg + (size_t)(qbase + (lane & 15)) * DH_ + kk * 32 + (lane >> 4) * 8);

  f32x4 acc[16];
#pragma unroll
  for (int f = 0; f < 16; f++) acc[f] = (f32x4){0.f, 0.f, 0.f, 0.f};
#pragma unroll
  for (int f = 0; f < 16; f++) {
#pragma unroll
    for (int kk = 0; kk < 2; kk++) {
      bfv8 bk = *(const bfv8*)(Kg + (size_t)(f * 16 + (lane & 15)) * DH_ + kk * 32 + (lane >> 4) * 8);
      acc[f] = __builtin_amdgcn_mfma_f32_16x16x32_bf16(aq[kk], bk, acc[f], 0, 0, 0);
    }
  }

  float cm[16];
#pragma unroll
  for (int f = 0; f < 16; f++)
    cm[f] = maskval(txt_mask, vis_mask, b, f * 16 + (lane & 15));

  const float scale = 0.125f;
#pragma unroll
  for (int j = 0; j < 4; j++) {
    const int qr = qbase + (lane >> 4) * 4 + j;
    const float qm = (qr < N_) ? maskval(txt_mask, vis_mask, b, qr) : 1.f;
    float sv[16];
    float mx = -3.0e38f;
#pragma unroll
    for (int f = 0; f < 16; f++) {
      const int col = f * 16 + (lane & 15);
      float sc;
      if (col >= N_) sc = -INFINITY;
      else if (qm * cm[f] == 0.f) sc = -1e30f;
      else sc = acc[f][j] * scale;
      sv[f] = sc;
      mx = fmaxf(mx, sc);
    }
#pragma unroll
    for (int d = 1; d < 16; d <<= 1) mx = fmaxf(mx, __shfl_xor(mx, d));
    float sum = 0.f;
#pragma unroll
    for (int f = 0; f < 16; f++) { const float p = expf(sv[f] - mx); sv[f] = p; sum += p; }
#pragma unroll
    for (int d = 1; d < 16; d <<= 1) sum += __shfl_xor(sum, d);
    const float inv = 1.f / sum;
    const int ql = wid * 16 + (lane >> 4) * 4 + j;
#pragma unroll
    for (int f = 0; f < 16; f++)
      Ps[ql * 264 + f * 16 + (lane & 15)] = (__bf16)(sv[f] * inv);
  }

  __syncthreads();

  f32x4 oacc[4];
#pragma unroll
  for (int n = 0; n < 4; n++) oacc[n] = (f32x4){0.f, 0.f, 0.f, 0.f};
#pragma unroll
  for (int kk = 0; kk < 8; kk++) {
    bfv8 ap = *(const bfv8*)&Ps[(wid * 16 + (lane & 15)) * 264 + kk * 32 + (lane >> 4) * 8];
#pragma unroll
    for (int n = 0; n < 4; n++) {
      bfv8 bv = *(const bfv8*)&Vt[(n * 16 + (lane & 15)) * 264 + kk * 32 + (lane >> 4) * 8];
      oacc[n] = __builtin_amdgcn_mfma_f32_16x16x32_bf16(ap, bv, oacc[n], 0, 0, 0);
    }
  }
#pragma unroll
  for (int n = 0; n < 4; n++)
#pragma unroll
    for (int j = 0; j < 4; j++) {
      const int q = qbase + (lane >> 4) * 4 + j;
      if (q < N_)
        ob[((size_t)b * N_ + q) * C_ + hh * 64 + n * 16 + (lane & 15)] =
            __float2bfloat16(oacc[n][j]);
    }
}

// ---------------- host ----------------
extern "C" void kernel_launch(void* const* d_in, const int* in_sizes, int n_in,
                              void* d_out, int out_size, void* d_ws, size_t ws_size,
                              hipStream_t stream) {
  const float* vis_in  = (const float*)d_in[0];
  const int*   txt_in  = (const int*)d_in[1];
  const int*   vis_mask = (const int*)d_in[2];
  const int*   txt_mask = (const int*)d_in[3];
  const float* patch_w = (const float*)d_in[4];
  const float* patch_b = (const float*)d_in[5];
  const float* w_embed = (const float*)d_in[6];
  const float* t_pos   = (const float*)d_in[7];
  const float* v_pos   = (const float*)d_in[8];
  const float* v_cls   = (const float*)d_in[9];
  const float* v_mod   = (const float*)d_in[10];
  const float* t_mod   = (const float*)d_in[11];
  const float* vn_w = (const float*)d_in[12];
  const float* vn_b = (const float*)d_in[13];
  const float* tn_w = (const float*)d_in[14];
  const float* tn_b = (const float*)d_in[15];
  const float* qkv_w = (const float*)d_in[16];
  const float* qkv_b = (const float*)d_in[17];
  const float* proj_w = (const float*)d_in[18];
  const float* proj_b = (const float*)d_in[19];
  const float* n1_w = (const float*)d_in[20];
  const float* n1_b = (const float*)d_in[21];
  const float* n2_w = (const float*)d_in[22];
  const float* n2_b = (const float*)d_in[23];
  const float* fc1_w = (const float*)d_in[24];
  const float* fc1_b = (const float*)d_in[25];
  const float* fc2_w = (const float*)d_in[26];
  const float* fc2_b = (const float*)d_in[27];

  char* ws = (char*)d_ws;
  if (ws_size < WS_NEED) {
    hipMemsetAsync(d_out, 0, (size_t)out_size * 4, stream);
    return;
  }
  float* x    = (float*)(ws + OFF_X);
  bf16* h     = (bf16*)(ws + OFF_H);
  bf16* qbuf  = (bf16*)(ws + OFF_Q);
  bf16* kbuf  = (bf16*)(ws + OFF_K);
  bf16* vbuf  = (bf16*)(ws + OFF_V);
  bf16* obuf  = (bf16*)(ws + OFF_O);
  bf16* ffh   = (bf16*)(ws + OFF_FFH);
  bf16* wq    = (bf16*)(ws + OFF_WB);
  bf16* wp    = wq + (size_t)2304 * 768;
  bf16* wf1   = wp + (size_t)768 * 768;
  bf16* wf2   = wf1 + (size_t)3072 * 768;
  float* ptmp = (float*)(ws + OFF_PTMP);
  bf16* visb  = (bf16*)(ws + OFF_VISB);
  bf16* pwb   = (bf16*)(ws + OFF_PWB);

  // patch projection
  f32_to_bf16_k<<<1024, 256, 0, stream>>>(vis_in, visb, (long)BP_ * C_ / 4);
  f32_to_bf16_k<<<256, 256, 0, stream>>>(patch_w, pwb, (long)C_ * C_ / 4);
  gemm_mb<0><<<(BP_ / 128) * (C_ / 128), 256, 0, stream>>>(
      visb, pwb, patch_b, ptmp, nullptr, nullptr, nullptr, nullptr, nullptr,
      C_, C_, BP_, C_ / 128);
  embed_kernel<<<MPAD, 256, 0, stream>>>(ptmp, txt_in, w_embed, t_pos, v_pos, v_cls,
                                         v_mod, t_mod, vn_w, vn_b, tn_w, tn_b, x);

  for (int l = 0; l < L_; l++) {
    conv_weights_k<<<2048, 256, 0, stream>>>(
        qkv_w + (size_t)l * 2304 * 768, proj_w + (size_t)l * 768 * 768,
        fc1_w + (size_t)l * 3072 * 768, fc2_w + (size_t)l * 768 * 3072, wq);

    ln_rows<<<MPAD / 4, 256, 0, stream>>>(x, n1_w + l * C_, n1_b + l * C_, h, 1e-6f);
    gemm_mb<1><<<(MPAD / 128) * (2304 / 128), 256, 0, stream>>>(
        h, wq, qkv_b + (size_t)l * 2304, nullptr, nullptr, nullptr, qbuf, kbuf, vbuf,
        2304, C_, M_, 2304 / 128);
    attn_fused<<<dim3(4, B_ * H_), 256, 0, stream>>>(qbuf, kbuf, vbuf, txt_mask,
                                                     vis_mask, obuf);
    gemm_mb<2><<<(MPAD / 128) * (C_ / 128), 256, 0, stream>>>(
        obuf, wp, proj_b + (size_t)l * C_, x, nullptr, nullptr, nullptr, nullptr,
        nullptr, C_, C_, M_, C_ / 128);
    ln_rows<<<MPAD / 4, 256, 0, stream>>>(x, n2_w + l * C_, n2_b + l * C_, h, 1e-6f);
    gemm_mb<3><<<(MPAD / 128) * (FF_ / 128), 256, 0, stream>>>(
        h, wf1, fc1_b + (size_t)l * FF_, nullptr, nullptr, ffh, nullptr, nullptr,
        nullptr, FF_, C_, M_, FF_ / 128);
    if (l < L_ - 1) {
      gemm_mb<2><<<(MPAD / 128) * (C_ / 128), 256, 0, stream>>>(
          ffh, wf2, fc2_b + (size_t)l * C_, x, nullptr, nullptr, nullptr, nullptr,
          nullptr, C_, FF_, M_, C_ / 128);
    } else {
      gemm_mb<4><<<(MPAD / 128) * (C_ / 128), 256, 0, stream>>>(
          ffh, wf2, fc2_b + (size_t)l * C_, x, (float*)d_out, nullptr, nullptr,
          nullptr, nullptr, C_, FF_, M_, C_ / 128);
    }
  }
}